// Round 6
// baseline (450.641 us; speedup 1.0000x reference)
//
#include <hip/hip_runtime.h>
#include <math.h>

// Problem: B=64, N_total=1029, D=768, r=64, E=4, TOPK=1.
// Fully fused, HIGH-TLP version (round 6):
//  - grid 2058 blocks x 256 thr; block = 32 tokens = 2 groups x 16.
//  - wave (g,u): phase1/3 compute N-half u for group g; phase2 duplicated
//    across the partner pair (cheap) -> exactly ONE __syncthreads.
//  - registers kept minimal (no deep prefetch queues): latency is hidden by
//    ~24 resident waves/CU instead of per-wave ILP (rounds 3-5 showed ILP
//    cannot cover it; occupancy was grid-capped at ~8 waves/CU).
//
// bf16x3 split: a*b ~= ah*bh + ah*bl + al*bh  (error ~2^-15 rel).
// Fragment map (A and B identical): lane (lg=l>>4,lr=l&15) holds
// M[lr][k0+lg*8+e], e=0..7.  C/D: col=lane&15, row=lg*4+reg [HW-verified].

#define GELU(v) (0.5f*(v)*(1.0f + erff((v)*0.70710678118654752440f)))

typedef __attribute__((ext_vector_type(8))) short bf16x8;
typedef __attribute__((ext_vector_type(4))) float f32x4;

#define MFMA(a,b,c) __builtin_amdgcn_mfma_f32_16x16x32_bf16((a),(b),(c),0,0,0)

__device__ __forceinline__ unsigned pk_hi(float a, float b) {
  return (__float_as_uint(a) >> 16) | (__float_as_uint(b) & 0xFFFF0000u);
}
__device__ __forceinline__ float f_lo(float a) {
  return a - __uint_as_float(__float_as_uint(a) & 0xFFFF0000u);
}
union U8 { unsigned u[4]; bf16x8 v; uint4 q; };
__device__ __forceinline__ bf16x8 hi8(float4 f0, float4 f1) {
  U8 r; r.u[0]=pk_hi(f0.x,f0.y); r.u[1]=pk_hi(f0.z,f0.w);
        r.u[2]=pk_hi(f1.x,f1.y); r.u[3]=pk_hi(f1.z,f1.w); return r.v;
}
__device__ __forceinline__ bf16x8 lo8(float4 f0, float4 f1) {
  U8 r; r.u[0]=pk_hi(f_lo(f0.x),f_lo(f0.y)); r.u[1]=pk_hi(f_lo(f0.z),f_lo(f0.w));
        r.u[2]=pk_hi(f_lo(f1.x),f_lo(f1.y)); r.u[3]=pk_hi(f_lo(f1.z),f_lo(f1.w)); return r.v;
}

// ---------------------------------------------------------------------------
// Fragment layout in wp (fid, 1 KB per fragment; value at (lane,e) =
// Bmat[col = tile*16+lr][k = kc*32 + lg*8 + e]):
//  fid   0..191 : Wd    fid = c*8 + nt*2 + part   (c = kt*2+kc, kt<12, nt<4)
//  fid 192..195 : Wg    fid = 192 + kc*2 + part   (cols 0..3 = experts, pad 0)
//  fid 200..263 : We    fid = 200 + (e*2+kc)*8 + j*2 + part   (j<4)
//  fid 264..455 : Wu    fid = 264 + nt*4 + kc*2 + part        (nt<48)
// ---------------------------------------------------------------------------
__global__ __launch_bounds__(256) void prep_pack(
    const float* __restrict__ Wd, const float* __restrict__ Wg,
    const float* __restrict__ We, const float* __restrict__ Wu,
    char* __restrict__ wp)
{
  int fid = blockIdx.x*4 + (threadIdx.x >> 6);
  if (fid >= 456) return;
  int l = threadIdx.x & 63, lg = l >> 4, lr = l & 15;
  float v[8];
  int part = 0;
  if (fid < 192) {
    int c = fid >> 3, s = fid & 7;
    int kt = c >> 1, kc = c & 1, nt = s >> 1; part = s & 1;
    const float* p = Wd + (size_t)(nt*16 + lr)*768 + kt*64 + kc*32 + lg*8;
    #pragma unroll
    for (int e = 0; e < 8; ++e) v[e] = p[e];
  } else if (fid < 264) {
    int f = fid - 192, ch = f >> 3, s = f & 7;
    if (ch == 0) {
      part = s & 1;
      int kc = (s >> 1) & 1;
      if (s < 4 && lr < 4) {
        const float* p = Wg + lr*64 + kc*32 + lg*8;
        #pragma unroll
        for (int e = 0; e < 8; ++e) v[e] = p[e];
      } else {
        #pragma unroll
        for (int e = 0; e < 8; ++e) v[e] = 0.f;
      }
    } else {
      int e_ = (ch - 1) >> 1, kc = (ch - 1) & 1, j = s >> 1; part = s & 1;
      const float* p = We + (size_t)(e_*64 + j*16 + lr)*64 + kc*32 + lg*8;
      #pragma unroll
      for (int e = 0; e < 8; ++e) v[e] = p[e];
    }
  } else {
    int f = fid - 264;
    int nt = f >> 2, kc = (f >> 1) & 1; part = f & 1;
    const float* p = Wu + (size_t)(nt*16 + lr)*64 + kc*32 + lg*8;
    #pragma unroll
    for (int e = 0; e < 8; ++e) v[e] = p[e];
  }
  U8 rr;
  if (part == 0) {
    rr.u[0]=pk_hi(v[0],v[1]); rr.u[1]=pk_hi(v[2],v[3]);
    rr.u[2]=pk_hi(v[4],v[5]); rr.u[3]=pk_hi(v[6],v[7]);
  } else {
    rr.u[0]=pk_hi(f_lo(v[0]),f_lo(v[1])); rr.u[1]=pk_hi(f_lo(v[2]),f_lo(v[3]));
    rr.u[2]=pk_hi(f_lo(v[4]),f_lo(v[5])); rr.u[3]=pk_hi(f_lo(v[6]),f_lo(v[7]));
  }
  *(uint4*)(wp + (size_t)fid*1024 + (size_t)l*16) = rr.q;
}

// ---------------------------------------------------------------------------
// Fused main kernel. Grid 2058 x 256. Block = 32 tokens (2 groups x 16).
// Wave wv: group g = wv>>1, N-half u = wv&1.
// ---------------------------------------------------------------------------
__global__ __launch_bounds__(256, 6) void fused(
    const float* __restrict__ x, const float* __restrict__ be,
    const float* __restrict__ gamma, const char* __restrict__ wp,
    float* __restrict__ out)
{
  __shared__ float sT[2][16][68];      // t per group (post-gelu)
  __shared__ float sFull[2][16][68];   // full per group
  const int tid = threadIdx.x, bm = blockIdx.x;
  const int wv = tid >> 6, l = tid & 63, lg = l >> 4, lr = l & 15;
  const int g = wv >> 1, u = wv & 1;
  const int tokg = bm*32 + g*16;       // group base token
  const char* wpL = wp + (size_t)l*16;

  // ---- phase 1: t(half u) = gelu(x . Wd[half u]^T) ----------------------
  const float* xrow = x + (size_t)(tokg + lr)*768 + lg*8;
  f32x4 t4[2];
  #pragma unroll
  for (int j = 0; j < 2; ++j)
    #pragma unroll
    for (int r = 0; r < 4; ++r) t4[j][r] = 0.f;

  #pragma unroll 2
  for (int c = 0; c < 24; ++c) {
    float4 f0 = *(const float4*)(xrow + c*32);
    float4 f1 = *(const float4*)(xrow + c*32 + 4);
    bf16x8 ah = hi8(f0, f1), al = lo8(f0, f1);
    const char* bp = wpL + (size_t)(c*8 + u*4)*1024;
    #pragma unroll
    for (int j = 0; j < 2; ++j) {
      bf16x8 bh = *(const bf16x8*)(bp + (size_t)(j*2)*1024);
      bf16x8 bl = *(const bf16x8*)(bp + (size_t)(j*2 + 1)*1024);
      t4[j] = MFMA(ah, bh, t4[j]);
      t4[j] = MFMA(ah, bl, t4[j]);
      t4[j] = MFMA(al, bh, t4[j]);
    }
  }
  #pragma unroll
  for (int j = 0; j < 2; ++j)
    #pragma unroll
    for (int r = 0; r < 4; ++r)
      sT[g][lg*4 + r][(u*2 + j)*16 + lr] = GELU(t4[j][r]);

  __syncthreads();    // the only block barrier: halves of t now combined

  // ---- phase 2: gating + experts (duplicated across partner waves) ------
  bf16x8 pah[2], pal[2];
  #pragma unroll
  for (int kc = 0; kc < 2; ++kc) {
    const float* ap = &sT[g][lr][kc*32 + lg*8];
    float4 a0 = *(const float4*)ap, a1 = *(const float4*)(ap + 4);
    pah[kc] = hi8(a0, a1); pal[kc] = lo8(a0, a1);
  }

  f32x4 lac;
  #pragma unroll
  for (int r = 0; r < 4; ++r) lac[r] = 0.f;
  {
    bf16x8 g0h = *(const bf16x8*)(wpL + (size_t)192*1024);
    bf16x8 g0l = *(const bf16x8*)(wpL + (size_t)193*1024);
    bf16x8 g1h = *(const bf16x8*)(wpL + (size_t)194*1024);
    bf16x8 g1l = *(const bf16x8*)(wpL + (size_t)195*1024);
    lac = MFMA(pah[0], g0h, lac); lac = MFMA(pah[0], g0l, lac); lac = MFMA(pal[0], g0h, lac);
    lac = MFMA(pah[1], g1h, lac); lac = MFMA(pah[1], g1l, lac); lac = MFMA(pal[1], g1h, lac);
  }
  float w_[4]; int ei_[4];
  #pragma unroll
  for (int r = 0; r < 4; ++r) {
    float lt = lac[r];
    int base = l & 48;
    float l0 = __shfl(lt, base + 0), l1 = __shfl(lt, base + 1);
    float l2 = __shfl(lt, base + 2), l3 = __shfl(lt, base + 3);
    int ei = 0; float lm = l0;
    if (l1 > lm) { lm = l1; ei = 1; }
    if (l2 > lm) { lm = l2; ei = 2; }
    if (l3 > lm) { lm = l3; ei = 3; }
    float s = expf(l0 - lm) + expf(l1 - lm) + expf(l2 - lm) + expf(l3 - lm);
    float w = 1.0f / s;
    int pos = (tokg + lg*4 + r) % 1029;   // first 5 tokens of each row: no MoE
    if (pos < 5) w = 0.0f;
    w_[r] = w; ei_[r] = ei;
  }

  f32x4 sel[4];
  #pragma unroll
  for (int j = 0; j < 4; ++j)
    #pragma unroll
    for (int r = 0; r < 4; ++r) sel[j][r] = 0.f;

  #pragma unroll
  for (int e = 0; e < 4; ++e) {
    #pragma unroll
    for (int jh = 0; jh < 2; ++jh) {        // j-halves: smaller live set
      f32x4 de[2];
      #pragma unroll
      for (int jj = 0; jj < 2; ++jj)
        #pragma unroll
        for (int r = 0; r < 4; ++r) de[jj][r] = 0.f;
      #pragma unroll
      for (int kc = 0; kc < 2; ++kc) {
        const char* bp = wpL + (size_t)(200 + (e*2 + kc)*8)*1024;
        #pragma unroll
        for (int jj = 0; jj < 2; ++jj) {
          const int j = jh*2 + jj;
          bf16x8 bh = *(const bf16x8*)(bp + (size_t)(j*2)*1024);
          bf16x8 bl = *(const bf16x8*)(bp + (size_t)(j*2 + 1)*1024);
          de[jj] = MFMA(pah[kc], bh, de[jj]);
          de[jj] = MFMA(pah[kc], bl, de[jj]);
          de[jj] = MFMA(pal[kc], bh, de[jj]);
        }
      }
      #pragma unroll
      for (int jj = 0; jj < 2; ++jj)
        #pragma unroll
        for (int r = 0; r < 4; ++r)
          sel[jh*2 + jj][r] = (ei_[r] == e) ? de[jj][r] : sel[jh*2 + jj][r];
    }
  }

  // full = t + w*(sel + be[ei]) -> sFull (partner writes identical values)
  #pragma unroll
  for (int r = 0; r < 4; ++r)
    #pragma unroll
    for (int j = 0; j < 4; ++j) {
      int col = j*16 + lr;
      float tv = sT[g][lg*4 + r][col];
      float bev = be[ei_[r]*64 + col];
      sFull[g][lg*4 + r][col] = tv + w_[r] * (sel[j][r] + bev);
    }

  // ---- phase 3: out(half u) = (full . Wu[half u]^T) * gamma -------------
  bf16x8 a3h[2], a3l[2];
  #pragma unroll
  for (int kc = 0; kc < 2; ++kc) {
    const float* ap = &sFull[g][lr][kc*32 + lg*8];
    float4 a0 = *(const float4*)ap, a1 = *(const float4*)(ap + 4);
    a3h[kc] = hi8(a0, a1); a3l[kc] = lo8(a0, a1);
  }

  #pragma unroll 2
  for (int q = 0; q < 24; ++q) {
    const int nt = u*24 + q;
    const char* bp = wpL + (size_t)(264 + nt*4)*1024;
    bf16x8 b0h = *(const bf16x8*)(bp);
    bf16x8 b0l = *(const bf16x8*)(bp + 1024);
    bf16x8 b1h = *(const bf16x8*)(bp + 2048);
    bf16x8 b1l = *(const bf16x8*)(bp + 3072);
    f32x4 o;
    #pragma unroll
    for (int r = 0; r < 4; ++r) o[r] = 0.f;
    o = MFMA(a3h[0], b0h, o); o = MFMA(a3h[0], b0l, o); o = MFMA(a3l[0], b0h, o);
    o = MFMA(a3h[1], b1h, o); o = MFMA(a3h[1], b1l, o); o = MFMA(a3l[1], b1h, o);
    const int col = nt*16 + lr;
    const float gv = gamma[col];
    #pragma unroll
    for (int r = 0; r < 4; ++r)
      out[(size_t)(tokg + lg*4 + r)*768 + col] = o[r] * gv;
  }
}

extern "C" void kernel_launch(void* const* d_in, const int* in_sizes, int n_in,
                              void* d_out, int out_size, void* d_ws, size_t ws_size,
                              hipStream_t stream) {
  const float* x     = (const float*)d_in[0];
  const float* Wd    = (const float*)d_in[1];
  const float* Wg    = (const float*)d_in[2];
  const float* We    = (const float*)d_in[3];
  const float* be    = (const float*)d_in[4];
  const float* Wu    = (const float*)d_in[5];
  const float* gamma = (const float*)d_in[6];
  float* out = (float*)d_out;
  char* wp   = (char*)d_ws;    // 456 KB packed weights

  prep_pack<<<114, 256, 0, stream>>>(Wd, Wg, We, Wu, wp);
  fused<<<2058, 256, 0, stream>>>(x, be, gamma, (const char*)wp, out);
}